// Round 9
// baseline (1011.771 us; speedup 1.0000x reference)
//
#include <hip/hip_runtime.h>

// Temporal GraphSAGE, P=4 periods, C=128, L=2 (reference constants).
// R8 = R7 + ONE __syncthreads() between the A2-half and the A1-from-LDS half.
// R7's failure: global_load_lds write extent (lane*16B) is invisible to alias
// analysis -> compiler skipped the vmcnt drain before the ds_reads; the
// barrier restores the canonical (m97) DMA->wait->read pattern, placed after
// ~64 MFMAs of A2 work so the DMA latency is already covered.
//  - A1: wave-private LDS staging, 8 coalesced 1KB global_load_lds
//  - A2: transposed aggt [kblock][row] -> coalesced direct loads, deg-masked
//  - B: direct global fragment loads ([step][col][quad], 1KB/instr, L2-hot)

#define CD 128

typedef __attribute__((ext_vector_type(8))) short s16x8;
typedef __attribute__((ext_vector_type(4))) float f32x4;

static __device__ __forceinline__ unsigned short f2bf(float f) {
  unsigned u = __float_as_uint(f);
  u += 0x7FFF + ((u >> 16) & 1);   // round-to-nearest-even
  return (unsigned short)(u >> 16);
}
static __device__ __forceinline__ float bf2f(unsigned us) {
  return __uint_as_float(us << 16);
}
static __device__ __forceinline__ void gload_lds16(const void* g, void* l) {
  __builtin_amdgcn_global_load_lds(
      (const __attribute__((address_space(1))) unsigned int*)g,
      (__attribute__((address_space(3))) unsigned int*)l, 16, 0, 0);
}

// ---- histogram: per-(period,dst) degree + involved bitmask ----
__global__ __launch_bounds__(256) void histk(const int* __restrict__ ntime,
    const int* __restrict__ eidx, int* __restrict__ deg_pd, int* __restrict__ involved,
    const int* __restrict__ minp, const int* __restrict__ up, int N, int E) {
  int e = blockIdx.x * 256 + threadIdx.x;
  if (e >= E) return;
  int s = eidx[e], d = eidx[E + e];
  int ts = ntime[s], td = ntime[d];
  int m = ts > td ? ts : td;
  int p = (m - minp[0]) / up[0];
  atomicAdd(&deg_pd[p * N + d], 1);
  atomicOr(&involved[s], 1 << p);
  atomicOr(&involved[d], 1 << p);
}

// ---- exclusive scan (3-phase) ----
__global__ __launch_bounds__(256) void scan1(const int* __restrict__ in,
    int* __restrict__ out, int* __restrict__ bsums, int M) {
  __shared__ int lds[256];
  int tid = threadIdx.x;
  int base = blockIdx.x * 1024 + tid * 4;
  int v0 = base + 0 < M ? in[base + 0] : 0;
  int v1 = base + 1 < M ? in[base + 1] : 0;
  int v2 = base + 2 < M ? in[base + 2] : 0;
  int v3 = base + 3 < M ? in[base + 3] : 0;
  int s = v0 + v1 + v2 + v3;
  lds[tid] = s;
  __syncthreads();
  for (int off = 1; off < 256; off <<= 1) {
    int t = tid >= off ? lds[tid - off] : 0;
    __syncthreads();
    lds[tid] += t;
    __syncthreads();
  }
  int run = lds[tid] - s;
  if (base + 0 < M) out[base + 0] = run; run += v0;
  if (base + 1 < M) out[base + 1] = run; run += v1;
  if (base + 2 < M) out[base + 2] = run; run += v2;
  if (base + 3 < M) out[base + 3] = run;
  if (tid == 255) bsums[blockIdx.x] = lds[255];
}

__global__ __launch_bounds__(256) void scan2(int* __restrict__ b, int M) {
  __shared__ int lds[256];
  int tid = threadIdx.x;
  int base = tid * 4;
  int v0 = base + 0 < M ? b[base + 0] : 0;
  int v1 = base + 1 < M ? b[base + 1] : 0;
  int v2 = base + 2 < M ? b[base + 2] : 0;
  int v3 = base + 3 < M ? b[base + 3] : 0;
  int s = v0 + v1 + v2 + v3;
  lds[tid] = s;
  __syncthreads();
  for (int off = 1; off < 256; off <<= 1) {
    int t = tid >= off ? lds[tid - off] : 0;
    __syncthreads();
    lds[tid] += t;
    __syncthreads();
  }
  int run = lds[tid] - s;
  if (base + 0 < M) b[base + 0] = run; run += v0;
  if (base + 1 < M) b[base + 1] = run; run += v1;
  if (base + 2 < M) b[base + 2] = run; run += v2;
  if (base + 3 < M) b[base + 3] = run;
}

__global__ __launch_bounds__(256) void scan3(int* __restrict__ out,
    const int* __restrict__ bsums, int M) {
  int add = bsums[blockIdx.x];
  int idx = blockIdx.x * 1024 + threadIdx.x;
#pragma unroll
  for (int k = 0; k < 4; ++k) {
    int i = idx + k * 256;
    if (i < M) out[i] += add;
  }
}

// ---- fill CSR col array; row_ptr doubles as cursor ----
__global__ __launch_bounds__(256) void fillk(const int* __restrict__ ntime,
    const int* __restrict__ eidx, int* __restrict__ row_ptr, int* __restrict__ col,
    const int* __restrict__ minp, const int* __restrict__ up, int N, int E) {
  int e = blockIdx.x * 256 + threadIdx.x;
  if (e >= E) return;
  int s = eidx[e], d = eidx[E + e];
  int ts = ntime[s], td = ntime[d];
  int m = ts > td ? ts : td;
  int p = (m - minp[0]) / up[0];
  int pos = atomicAdd(&row_ptr[p * N + d], 1);
  col[pos] = s;
}

// ---- weights: transpose + bf16, [step][col][quad] fragment layout ----
// 16B block ((s*128 + n)*4 + quad); content k = (s*4+quad)*8 + j,
// k<128 from w_root[l][k][n], else w_nbr[l][k-128][n].
__global__ __launch_bounds__(256) void wprep(const float* __restrict__ wroot,
    const float* __restrict__ wnbr, unsigned short* __restrict__ wt, int total) {
  int t = blockIdx.x * 256 + threadIdx.x;
  if (t >= total) return;
  int l = t >> 12;
  int rem = t & 4095;
  int s = rem >> 9;
  int rem2 = rem & 511;
  int n = rem2 >> 2;
  int quad = rem2 & 3;
  const float* w0 = wroot + l * CD * CD;
  const float* w1 = wnbr + l * CD * CD;
  unsigned short o[8];
#pragma unroll
  for (int j = 0; j < 8; ++j) {
    int k = (s * 4 + quad) * 8 + j;
    float v = (k < CD) ? w0[k * CD + n] : w1[(k - CD) * CD + n];
    o[j] = f2bf(v);
  }
  uint4 pk;
  pk.x = (unsigned)o[0] | ((unsigned)o[1] << 16);
  pk.y = (unsigned)o[2] | ((unsigned)o[3] << 16);
  pk.z = (unsigned)o[4] | ((unsigned)o[5] << 16);
  pk.w = (unsigned)o[6] | ((unsigned)o[7] << 16);
  *(uint4*)(wt + (size_t)l * 32768 + (((size_t)s * CD + n) * 4 + quad) * 8) = pk;
}

// ---- x_bf init (+ fp32 mirror of seed rows for the head) ----
__global__ __launch_bounds__(256) void xprep(const float* __restrict__ x,
    float* __restrict__ x32, unsigned short* __restrict__ xb, int nseed, int total4) {
  int t = blockIdx.x * 256 + threadIdx.x;
  if (t >= total4) return;
  size_t i = (size_t)t * 4;
  float4 v = *(const float4*)(x + i);
  uint2 pk;
  pk.x = (unsigned)f2bf(v.x) | ((unsigned)f2bf(v.y) << 16);
  pk.y = (unsigned)f2bf(v.z) | ((unsigned)f2bf(v.w) << 16);
  *(uint2*)(xb + i) = pk;
  if ((int)(i >> 7) < nseed) *(float4*)(x32 + i) = v;
}

// ---- pull aggregation: 16-lane group per dst; OUTPUT TRANSPOSED:
// aggt[kb*N + d] (16B block kb = channels kb*8..kb*8+7). deg==0 skipped. ----
__global__ __launch_bounds__(256) void aggk(const unsigned short* __restrict__ hbf,
    unsigned short* __restrict__ aggt, const int* __restrict__ row_ptr,
    const int* __restrict__ deg_pd, const int* __restrict__ col, int p, int N) {
  int d = blockIdx.x * 16 + (threadIdx.x >> 4);
  if (d >= N) return;
  int lane = threadIdx.x & 15;   // = kb
  int key = p * N + d;
  int dg = deg_pd[key];
  if (dg == 0) return;           // gemm zero-masks these rows in registers
  int start = row_ptr[key] - dg;
  float a[8];
#pragma unroll
  for (int i = 0; i < 8; ++i) a[i] = 0.f;
  for (int j = 0; j < dg; ++j) {
    int s = col[start + j];
    uint4 r = *(const uint4*)(hbf + (size_t)s * CD + lane * 8);
    a[0] += bf2f(r.x & 0xffffu); a[1] += bf2f(r.x >> 16);
    a[2] += bf2f(r.y & 0xffffu); a[3] += bf2f(r.y >> 16);
    a[4] += bf2f(r.z & 0xffffu); a[5] += bf2f(r.z >> 16);
    a[6] += bf2f(r.w & 0xffffu); a[7] += bf2f(r.w >> 16);
  }
  float sc = 1.0f / (float)dg;
  uint4 outv;
  outv.x = (unsigned)f2bf(a[0] * sc) | ((unsigned)f2bf(a[1] * sc) << 16);
  outv.y = (unsigned)f2bf(a[2] * sc) | ((unsigned)f2bf(a[3] * sc) << 16);
  outv.z = (unsigned)f2bf(a[4] * sc) | ((unsigned)f2bf(a[5] * sc) << 16);
  outv.w = (unsigned)f2bf(a[6] * sc) | ((unsigned)f2bf(a[7] * sc) << 16);
  *(uint4*)(aggt + ((size_t)lane * N + d) * 8) = outv;
}

// ---- MFMA GEMM + bias + LN (+relu -> h_bf | +residual -> x_bf [& x32 seeds]) ----
// 256 threads = 4 waves; block tile 128x128; wave = 32 rows x 128 cols
// = 2x8 tiles of 16x16x32. K=256 = [A1 | agg]. ONE barrier:
//   issue A1 DMA -> load a2f/B -> A2-half MFMAs -> __syncthreads (drains
//   DMA, m97 pattern) -> A1-half from wave-private LDS.
__global__ __launch_bounds__(256, 3) void gemm_mfma(
    const unsigned short* __restrict__ A1, const unsigned short* __restrict__ aggt,
    const int* __restrict__ degp,
    const unsigned short* __restrict__ wt,
    const float* __restrict__ bias, const float* __restrict__ lng,
    const float* __restrict__ lnb,
    unsigned short* __restrict__ hout,
    float* __restrict__ x32, unsigned short* __restrict__ xbf,
    const int* __restrict__ involved, int pbit, int mode, int nseed, int N) {
  __shared__ unsigned char alds[4 * 8320];   // 4 waves x 8 x (1024+16)
  int tid = threadIdx.x;
  int w = tid >> 6;
  int lane = tid & 63;
  int l15 = lane & 15;
  int quad = lane >> 4;
  int rbase = blockIdx.x * 128;
  unsigned char* wlds = alds + w * 8320;

  // ---- A1 DMA: 8 coalesced 1KB instructions (4 contiguous rows each) ----
#pragma unroll
  for (int i = 0; i < 8; ++i) {
    int g0 = rbase + w * 32 + i * 4;
    if (g0 > N - 4) g0 = N - 4;
    gload_lds16(A1 + (size_t)g0 * CD + lane * 8, wlds + i * 1040);
  }

  int row[2];
  bool hasdeg[2];
#pragma unroll
  for (int rt = 0; rt < 2; ++rt) {
    int r = rbase + w * 32 + rt * 16 + l15;
    row[rt] = r < N ? r : N - 1;
    hasdeg[rt] = degp[row[rt]] > 0;
  }

  // ---- A2 fragments from transposed agg (coalesced); mask deg==0 rows ----
  s16x8 a2f[2][4];
#pragma unroll
  for (int rt = 0; rt < 2; ++rt)
#pragma unroll
    for (int f = 0; f < 4; ++f) {
      int kb = f * 4 + quad;
      s16x8 t = *(const s16x8*)(aggt + ((size_t)kb * N + row[rt]) * 8);
      a2f[rt][f] = hasdeg[rt] ? t : (s16x8)(short)0;
    }

  f32x4 acc[2][8];
#pragma unroll
  for (int rt = 0; rt < 2; ++rt)
#pragma unroll
    for (int ct = 0; ct < 8; ++ct) acc[rt][ct] = (f32x4)(0.f);

  // ---- half 1: agg columns of K (B steps 4..7), A in registers ----
#pragma unroll
  for (int ks = 0; ks < 4; ++ks) {
    int s = 4 + ks;
    s16x8 b[8];
#pragma unroll
    for (int ct = 0; ct < 8; ++ct)
      b[ct] = *(const s16x8*)(wt + (((size_t)s * CD + ct * 16 + l15) * 4 + quad) * 8);
#pragma unroll
    for (int rt = 0; rt < 2; ++rt)
#pragma unroll
      for (int ct = 0; ct < 8; ++ct)
        acc[rt][ct] = __builtin_amdgcn_mfma_f32_16x16x32_bf16(
            a2f[rt][ks], b[ct], acc[rt][ct], 0, 0, 0);
  }

  // ---- barrier: drains the A1 LDS-DMA (compiler emits vmcnt(0) before
  // s_barrier). Placed after 64 MFMAs so the DMA latency is already hidden.
  __syncthreads();

  // ---- half 2: A1 from wave-private LDS (B steps 0..3) ----
#pragma unroll
  for (int ks = 0; ks < 4; ++ks) {
    s16x8 b[8];
#pragma unroll
    for (int ct = 0; ct < 8; ++ct)
      b[ct] = *(const s16x8*)(wt + (((size_t)ks * CD + ct * 16 + l15) * 4 + quad) * 8);
    s16x8 af[2];
#pragma unroll
    for (int rt = 0; rt < 2; ++rt) {
      int r = rt * 16 + l15;
      af[rt] = *(const s16x8*)(wlds + (r >> 2) * 1040 + (r & 3) * 256 +
                               (ks * 4 + quad) * 16);
    }
#pragma unroll
    for (int rt = 0; rt < 2; ++rt)
#pragma unroll
      for (int ct = 0; ct < 8; ++ct)
        acc[rt][ct] = __builtin_amdgcn_mfma_f32_16x16x32_bf16(
            af[rt], b[ct], acc[rt][ct], 0, 0, 0);
  }

  // ---- epilogue: bias + LayerNorm across the 16-lane row group ----
  float bb[8], gg[8], eb[8];
#pragma unroll
  for (int ct = 0; ct < 8; ++ct) {
    int c = ct * 16 + l15;
    bb[ct] = bias[c]; gg[ct] = lng[c]; eb[ct] = lnb[c];
  }
#pragma unroll
  for (int rt = 0; rt < 2; ++rt) {
#pragma unroll
    for (int reg = 0; reg < 4; ++reg) {
      int r = rbase + w * 32 + rt * 16 + quad * 4 + reg;
      float vals[8];
      float s = 0.f, ss = 0.f;
#pragma unroll
      for (int ct = 0; ct < 8; ++ct) {
        float v = acc[rt][ct][reg] + bb[ct];
        vals[ct] = v;
        s += v; ss += v * v;
      }
#pragma unroll
      for (int m = 1; m <= 8; m <<= 1) {
        s  += __shfl_xor(s, m, 64);
        ss += __shfl_xor(ss, m, 64);
      }
      float mu  = s * (1.0f / CD);
      float var = ss * (1.0f / CD) - mu * mu;
      float rs  = rsqrtf(var + 1e-5f);
      if (r < N) {
        if (mode == 0) {
#pragma unroll
          for (int ct = 0; ct < 8; ++ct) {
            float o = (vals[ct] - mu) * rs * gg[ct] + eb[ct];
            o = fmaxf(o, 0.f);
            hout[(size_t)r * CD + ct * 16 + l15] = f2bf(o);
          }
        } else if ((involved[r] >> pbit) & 1) {
          bool seed = r < nseed;
#pragma unroll
          for (int ct = 0; ct < 8; ++ct) {
            float o = (vals[ct] - mu) * rs * gg[ct] + eb[ct];
            size_t idx = (size_t)r * CD + ct * 16 + l15;
            float xn = bf2f(xbf[idx]) + o;
            xbf[idx] = f2bf(xn);
            if (seed) x32[idx] += o;
          }
        }
      }
    }
  }
}

// ---- head (reads fp32 seed mirror) ----
__global__ __launch_bounds__(256) void headk(const float* __restrict__ x,
    const float* __restrict__ hw, const float* __restrict__ hb,
    float* __restrict__ out, int seeds) {
  int wave = threadIdx.x >> 6;
  int lane = threadIdx.x & 63;
  int row = blockIdx.x * 4 + wave;
  if (row >= seeds) return;
  const float* xp = x + (size_t)row * CD;
  float v = xp[lane] * hw[lane] + xp[64 + lane] * hw[64 + lane];
#pragma unroll
  for (int m = 1; m < 64; m <<= 1) v += __shfl_xor(v, m, 64);
  if (lane == 0) out[row] = v + hb[0];
}

extern "C" void kernel_launch(void* const* d_in, const int* in_sizes, int n_in,
                              void* d_out, int out_size, void* d_ws, size_t ws_size,
                              hipStream_t stream) {
  const float* x     = (const float*)d_in[0];
  const int*   ntime = (const int*)d_in[1];
  const int*   eidx  = (const int*)d_in[2];
  const float* wroot = (const float*)d_in[3];
  const float* wnbr  = (const float*)d_in[4];
  const float* bias  = (const float*)d_in[5];
  const float* lng   = (const float*)d_in[6];
  const float* lnb   = (const float*)d_in[7];
  const float* headw = (const float*)d_in[8];
  const float* headb = (const float*)d_in[9];
  const int*   minp  = (const int*)d_in[10];
  const int*   up    = (const int*)d_in[12];

  int N = in_sizes[0] / CD;
  int E = in_sizes[2] / 2;
  const int P = 4;
  int M = P * N;
  int nseed = out_size;   // OUT=1 per reference

  size_t off = 0;
  auto alloc = [&](size_t bytes) {
    void* p = (char*)d_ws + off;
    off += (bytes + 255) & ~(size_t)255;
    return p;
  };
  unsigned short* x_bf   = (unsigned short*)alloc((size_t)N * CD * 2);
  unsigned short* h_bf   = (unsigned short*)alloc((size_t)N * CD * 2);
  unsigned short* agg_t  = (unsigned short*)alloc((size_t)N * CD * 2);
  float*          x32    = (float*)alloc((size_t)nseed * CD * 4);
  unsigned short* wt     = (unsigned short*)alloc(2 * 32768 * 2);
  int* deg_pd   = (int*)alloc((size_t)M * 4);
  int* row_ptr  = (int*)alloc((size_t)M * 4);
  int* col      = (int*)alloc((size_t)E * 4);
  int* involved = (int*)alloc((size_t)N * 4);
  int* bsums    = (int*)alloc(4096);
  (void)ws_size;

  hipMemsetAsync(deg_pd, 0, (size_t)M * 4, stream);
  hipMemsetAsync(involved, 0, (size_t)N * 4, stream);

  int egrid = (E + 255) / 256;
  int NB = (M + 1023) / 1024;
  int ggrid = (N + 127) / 128;
  int agrid = (N + 15) / 16;

  xprep<<<(N * 32 + 255) / 256, 256, 0, stream>>>(x, x32, x_bf, nseed, N * 32);
  wprep<<<(8192 + 255) / 256, 256, 0, stream>>>(wroot, wnbr, wt, 8192);
  histk<<<egrid, 256, 0, stream>>>(ntime, eidx, deg_pd, involved, minp, up, N, E);
  scan1<<<NB, 256, 0, stream>>>(deg_pd, row_ptr, bsums, M);
  scan2<<<1, 256, 0, stream>>>(bsums, NB);
  scan3<<<NB, 256, 0, stream>>>(row_ptr, bsums, M);
  fillk<<<egrid, 256, 0, stream>>>(ntime, eidx, row_ptr, col, minp, up, N, E);

  for (int p = 0; p < P; ++p) {
    const int* degp = deg_pd + (size_t)p * N;
    aggk<<<agrid, 256, 0, stream>>>(x_bf, agg_t, row_ptr, deg_pd, col, p, N);
    gemm_mfma<<<ggrid, 256, 0, stream>>>(x_bf, agg_t, degp, wt,
        bias, lng, lnb, h_bf, nullptr, nullptr, nullptr, -1, 0, nseed, N);
    aggk<<<agrid, 256, 0, stream>>>(h_bf, agg_t, row_ptr, deg_pd, col, p, N);
    gemm_mfma<<<ggrid, 256, 0, stream>>>(h_bf, agg_t, degp, wt + 32768,
        bias + CD, lng + CD, lnb + CD, nullptr, x32, x_bf, involved, p, 1, nseed, N);
  }
  headk<<<(nseed + 3) / 4, 256, 0, stream>>>(x32, headw, headb, (float*)d_out, nseed);
}

// Round 10
// 998.442 us; speedup vs baseline: 1.0133x; 1.0133x over previous
//
#include <hip/hip_runtime.h>

// Temporal GraphSAGE, P=4 periods, C=128, L=2 (reference constants).
// R9 = R8 core + involved-row compaction (gemm only runs rows of period p's
// involved set, via per-period row lists + gather-DMA) + coalesced epilogue
// (LDS fp32 transpose -> 256B row-major stores instead of 2B scatter).
// agg back to row-major (rows are gathered now anyway).

#define CD 128

typedef __attribute__((ext_vector_type(8))) short s16x8;
typedef __attribute__((ext_vector_type(4))) float f32x4;

static __device__ __forceinline__ unsigned short f2bf(float f) {
  unsigned u = __float_as_uint(f);
  u += 0x7FFF + ((u >> 16) & 1);   // round-to-nearest-even
  return (unsigned short)(u >> 16);
}
static __device__ __forceinline__ float bf2f(unsigned us) {
  return __uint_as_float(us << 16);
}
static __device__ __forceinline__ void gload_lds16(const void* g, void* l) {
  __builtin_amdgcn_global_load_lds(
      (const __attribute__((address_space(1))) unsigned int*)g,
      (__attribute__((address_space(3))) unsigned int*)l, 16, 0, 0);
}

// ---- histogram: per-(period,dst) degree + involved bitmask ----
__global__ __launch_bounds__(256) void histk(const int* __restrict__ ntime,
    const int* __restrict__ eidx, int* __restrict__ deg_pd, int* __restrict__ involved,
    const int* __restrict__ minp, const int* __restrict__ up, int N, int E) {
  int e = blockIdx.x * 256 + threadIdx.x;
  if (e >= E) return;
  int s = eidx[e], d = eidx[E + e];
  int ts = ntime[s], td = ntime[d];
  int m = ts > td ? ts : td;
  int p = (m - minp[0]) / up[0];
  atomicAdd(&deg_pd[p * N + d], 1);
  atomicOr(&involved[s], 1 << p);
  atomicOr(&involved[d], 1 << p);
}

// ---- per-period compacted involved-row lists ----
__global__ __launch_bounds__(256) void listk(const int* __restrict__ involved,
    int* __restrict__ lists, int* __restrict__ cnt, int N) {
  int n = blockIdx.x * 256 + threadIdx.x;
  if (n >= N) return;
  int m = involved[n];
#pragma unroll
  for (int p = 0; p < 4; ++p)
    if ((m >> p) & 1) {
      int pos = atomicAdd(&cnt[p], 1);   // wave-coalesced by compiler
      lists[p * N + pos] = n;
    }
}

// ---- exclusive scan (3-phase) ----
__global__ __launch_bounds__(256) void scan1(const int* __restrict__ in,
    int* __restrict__ out, int* __restrict__ bsums, int M) {
  __shared__ int lds[256];
  int tid = threadIdx.x;
  int base = blockIdx.x * 1024 + tid * 4;
  int v0 = base + 0 < M ? in[base + 0] : 0;
  int v1 = base + 1 < M ? in[base + 1] : 0;
  int v2 = base + 2 < M ? in[base + 2] : 0;
  int v3 = base + 3 < M ? in[base + 3] : 0;
  int s = v0 + v1 + v2 + v3;
  lds[tid] = s;
  __syncthreads();
  for (int off = 1; off < 256; off <<= 1) {
    int t = tid >= off ? lds[tid - off] : 0;
    __syncthreads();
    lds[tid] += t;
    __syncthreads();
  }
  int run = lds[tid] - s;
  if (base + 0 < M) out[base + 0] = run; run += v0;
  if (base + 1 < M) out[base + 1] = run; run += v1;
  if (base + 2 < M) out[base + 2] = run; run += v2;
  if (base + 3 < M) out[base + 3] = run;
  if (tid == 255) bsums[blockIdx.x] = lds[255];
}

__global__ __launch_bounds__(256) void scan2(int* __restrict__ b, int M) {
  __shared__ int lds[256];
  int tid = threadIdx.x;
  int base = tid * 4;
  int v0 = base + 0 < M ? b[base + 0] : 0;
  int v1 = base + 1 < M ? b[base + 1] : 0;
  int v2 = base + 2 < M ? b[base + 2] : 0;
  int v3 = base + 3 < M ? b[base + 3] : 0;
  int s = v0 + v1 + v2 + v3;
  lds[tid] = s;
  __syncthreads();
  for (int off = 1; off < 256; off <<= 1) {
    int t = tid >= off ? lds[tid - off] : 0;
    __syncthreads();
    lds[tid] += t;
    __syncthreads();
  }
  int run = lds[tid] - s;
  if (base + 0 < M) b[base + 0] = run; run += v0;
  if (base + 1 < M) b[base + 1] = run; run += v1;
  if (base + 2 < M) b[base + 2] = run; run += v2;
  if (base + 3 < M) b[base + 3] = run;
}

__global__ __launch_bounds__(256) void scan3(int* __restrict__ out,
    const int* __restrict__ bsums, int M) {
  int add = bsums[blockIdx.x];
  int idx = blockIdx.x * 1024 + threadIdx.x;
#pragma unroll
  for (int k = 0; k < 4; ++k) {
    int i = idx + k * 256;
    if (i < M) out[i] += add;
  }
}

// ---- fill CSR col array; row_ptr doubles as cursor ----
__global__ __launch_bounds__(256) void fillk(const int* __restrict__ ntime,
    const int* __restrict__ eidx, int* __restrict__ row_ptr, int* __restrict__ col,
    const int* __restrict__ minp, const int* __restrict__ up, int N, int E) {
  int e = blockIdx.x * 256 + threadIdx.x;
  if (e >= E) return;
  int s = eidx[e], d = eidx[E + e];
  int ts = ntime[s], td = ntime[d];
  int m = ts > td ? ts : td;
  int p = (m - minp[0]) / up[0];
  int pos = atomicAdd(&row_ptr[p * N + d], 1);
  col[pos] = s;
}

// ---- weights: transpose + bf16, [step][col][quad] fragment layout ----
__global__ __launch_bounds__(256) void wprep(const float* __restrict__ wroot,
    const float* __restrict__ wnbr, unsigned short* __restrict__ wt, int total) {
  int t = blockIdx.x * 256 + threadIdx.x;
  if (t >= total) return;
  int l = t >> 12;
  int rem = t & 4095;
  int s = rem >> 9;
  int rem2 = rem & 511;
  int n = rem2 >> 2;
  int quad = rem2 & 3;
  const float* w0 = wroot + l * CD * CD;
  const float* w1 = wnbr + l * CD * CD;
  unsigned short o[8];
#pragma unroll
  for (int j = 0; j < 8; ++j) {
    int k = (s * 4 + quad) * 8 + j;
    float v = (k < CD) ? w0[k * CD + n] : w1[(k - CD) * CD + n];
    o[j] = f2bf(v);
  }
  uint4 pk;
  pk.x = (unsigned)o[0] | ((unsigned)o[1] << 16);
  pk.y = (unsigned)o[2] | ((unsigned)o[3] << 16);
  pk.z = (unsigned)o[4] | ((unsigned)o[5] << 16);
  pk.w = (unsigned)o[6] | ((unsigned)o[7] << 16);
  *(uint4*)(wt + (size_t)l * 32768 + (((size_t)s * CD + n) * 4 + quad) * 8) = pk;
}

// ---- x_bf init (+ fp32 mirror of seed rows for the head) ----
__global__ __launch_bounds__(256) void xprep(const float* __restrict__ x,
    float* __restrict__ x32, unsigned short* __restrict__ xb, int nseed, int total4) {
  int t = blockIdx.x * 256 + threadIdx.x;
  if (t >= total4) return;
  size_t i = (size_t)t * 4;
  float4 v = *(const float4*)(x + i);
  uint2 pk;
  pk.x = (unsigned)f2bf(v.x) | ((unsigned)f2bf(v.y) << 16);
  pk.y = (unsigned)f2bf(v.z) | ((unsigned)f2bf(v.w) << 16);
  *(uint2*)(xb + i) = pk;
  if ((int)(i >> 7) < nseed) *(float4*)(x32 + i) = v;
}

// ---- pull aggregation: 16-lane group per dst, row-major agg out, deg>0 only ----
__global__ __launch_bounds__(256) void aggk(const unsigned short* __restrict__ hbf,
    unsigned short* __restrict__ agg, const int* __restrict__ row_ptr,
    const int* __restrict__ deg_pd, const int* __restrict__ col, int p, int N) {
  int d = blockIdx.x * 16 + (threadIdx.x >> 4);
  if (d >= N) return;
  int lane = threadIdx.x & 15;
  int key = p * N + d;
  int dg = deg_pd[key];
  if (dg == 0) return;           // gemm zero-masks these rows in registers
  int start = row_ptr[key] - dg;
  float a[8];
#pragma unroll
  for (int i = 0; i < 8; ++i) a[i] = 0.f;
  for (int j = 0; j < dg; ++j) {
    int s = col[start + j];
    uint4 r = *(const uint4*)(hbf + (size_t)s * CD + lane * 8);
    a[0] += bf2f(r.x & 0xffffu); a[1] += bf2f(r.x >> 16);
    a[2] += bf2f(r.y & 0xffffu); a[3] += bf2f(r.y >> 16);
    a[4] += bf2f(r.z & 0xffffu); a[5] += bf2f(r.z >> 16);
    a[6] += bf2f(r.w & 0xffffu); a[7] += bf2f(r.w >> 16);
  }
  float sc = 1.0f / (float)dg;
  uint4 outv;
  outv.x = (unsigned)f2bf(a[0] * sc) | ((unsigned)f2bf(a[1] * sc) << 16);
  outv.y = (unsigned)f2bf(a[2] * sc) | ((unsigned)f2bf(a[3] * sc) << 16);
  outv.z = (unsigned)f2bf(a[4] * sc) | ((unsigned)f2bf(a[5] * sc) << 16);
  outv.w = (unsigned)f2bf(a[6] * sc) | ((unsigned)f2bf(a[7] * sc) << 16);
  *(uint4*)(agg + (size_t)d * CD + lane * 8) = outv;
}

// ---- MFMA GEMM on the period's involved-row list ----
// 256 threads = 4 waves; tile = 128 list-rows x 128 cols; wave = 32 rows.
// K=256 = [A1(list rows) | agg(list rows)]. A1 via gather-DMA into
// wave-private LDS; a2f direct gathered 16B loads (deg-masked); B direct
// global (L2-hot). One barrier (DMA drain). Epilogue: LN then LDS fp32
// transpose (2 passes x 16 rows, reusing the A1 buffer) -> coalesced 256B
// row-major stores (mode 0: relu->hout; mode 1: xbf RMW + x32 for seeds).
__global__ __launch_bounds__(256) void gemm_mfma(
    const unsigned short* __restrict__ A1, const unsigned short* __restrict__ agg,
    const int* __restrict__ degp,
    const unsigned short* __restrict__ wt,
    const float* __restrict__ bias, const float* __restrict__ lng,
    const float* __restrict__ lnb,
    unsigned short* __restrict__ hout,
    float* __restrict__ x32, unsigned short* __restrict__ xbf,
    const int* __restrict__ list, const int* __restrict__ cntp,
    int mode, int nseed, int N) {
  __shared__ unsigned char alds[4 * 8320];   // 4 waves x (8KB rows + pad)
  int cnt = cntp[0];
  int rbase = blockIdx.x * 128;
  if (rbase >= cnt) return;
  int tid = threadIdx.x;
  int w = tid >> 6;
  int lane = tid & 63;
  int l15 = lane & 15;
  int quad = lane >> 4;
  unsigned char* wlds = alds + w * 8320;

  // ---- A1 gather-DMA: 8 x 1KB, 4 list-rows each (256B segments) ----
#pragma unroll
  for (int i = 0; i < 8; ++i) {
    int li = rbase + w * 32 + i * 4 + (lane >> 4);
    if (li >= cnt) li = cnt - 1;
    int gr = list[li];
    gload_lds16(A1 + (size_t)gr * CD + (lane & 15) * 8, wlds + i * 1040);
  }

  // fragment rows (local -> global via list)
  int grow[2];
  bool hasdeg[2];
#pragma unroll
  for (int rt = 0; rt < 2; ++rt) {
    int li = rbase + w * 32 + rt * 16 + l15;
    if (li >= cnt) li = cnt - 1;
    grow[rt] = list[li];
    hasdeg[rt] = degp[grow[rt]] > 0;
  }

  // ---- A2 fragments gathered from row-major agg; mask deg==0 rows ----
  s16x8 a2f[2][4];
#pragma unroll
  for (int rt = 0; rt < 2; ++rt)
#pragma unroll
    for (int f = 0; f < 4; ++f) {
      s16x8 t = *(const s16x8*)(agg + (size_t)grow[rt] * CD + (f * 4 + quad) * 8);
      a2f[rt][f] = hasdeg[rt] ? t : (s16x8)(short)0;
    }

  f32x4 acc[2][8];
#pragma unroll
  for (int rt = 0; rt < 2; ++rt)
#pragma unroll
    for (int ct = 0; ct < 8; ++ct) acc[rt][ct] = (f32x4)(0.f);

  // ---- half 1: agg columns of K (B steps 4..7) ----
#pragma unroll
  for (int ks = 0; ks < 4; ++ks) {
    int s = 4 + ks;
    s16x8 b[8];
#pragma unroll
    for (int ct = 0; ct < 8; ++ct)
      b[ct] = *(const s16x8*)(wt + (((size_t)s * CD + ct * 16 + l15) * 4 + quad) * 8);
#pragma unroll
    for (int rt = 0; rt < 2; ++rt)
#pragma unroll
      for (int ct = 0; ct < 8; ++ct)
        acc[rt][ct] = __builtin_amdgcn_mfma_f32_16x16x32_bf16(
            a2f[rt][ks], b[ct], acc[rt][ct], 0, 0, 0);
  }

  __syncthreads();   // drains the A1 gather-DMA (m97 pattern)

  // ---- half 2: A1 from wave-private LDS (B steps 0..3) ----
#pragma unroll
  for (int ks = 0; ks < 4; ++ks) {
    s16x8 b[8];
#pragma unroll
    for (int ct = 0; ct < 8; ++ct)
      b[ct] = *(const s16x8*)(wt + (((size_t)ks * CD + ct * 16 + l15) * 4 + quad) * 8);
    s16x8 af[2];
#pragma unroll
    for (int rt = 0; rt < 2; ++rt) {
      int r = rt * 16 + l15;
      af[rt] = *(const s16x8*)(wlds + (r >> 2) * 1040 + (r & 3) * 256 +
                               (ks * 4 + quad) * 16);
    }
#pragma unroll
    for (int rt = 0; rt < 2; ++rt)
#pragma unroll
      for (int ct = 0; ct < 8; ++ct)
        acc[rt][ct] = __builtin_amdgcn_mfma_f32_16x16x32_bf16(
            af[rt], b[ct], acc[rt][ct], 0, 0, 0);
  }

  // ---- epilogue: bias + LN (16-lane shfl), then LDS fp32 transpose ----
  float bb[8], gg[8], eb[8];
#pragma unroll
  for (int ct = 0; ct < 8; ++ct) {
    int c = ct * 16 + l15;
    bb[ct] = bias[c]; gg[ct] = lng[c]; eb[ct] = lnb[c];
  }
  float* tb = (float*)wlds;   // 16 rows x 128 fp32 = 8KB, wave-private reuse
#pragma unroll
  for (int rt = 0; rt < 2; ++rt) {
#pragma unroll
    for (int reg = 0; reg < 4; ++reg) {
      float vals[8];
      float s = 0.f, ss = 0.f;
#pragma unroll
      for (int ct = 0; ct < 8; ++ct) {
        float v = acc[rt][ct][reg] + bb[ct];
        vals[ct] = v;
        s += v; ss += v * v;
      }
#pragma unroll
      for (int m = 1; m <= 8; m <<= 1) {
        s  += __shfl_xor(s, m, 64);
        ss += __shfl_xor(ss, m, 64);
      }
      float mu  = s * (1.0f / CD);
      float var = ss * (1.0f / CD) - mu * mu;
      float rs  = rsqrtf(var + 1e-5f);
#pragma unroll
      for (int ct = 0; ct < 8; ++ct) {
        float o = (vals[ct] - mu) * rs * gg[ct] + eb[ct];
        if (mode == 0) o = fmaxf(o, 0.f);
        tb[(quad * 4 + reg) * CD + ct * 16 + l15] = o;
      }
    }
    // read back row-major (2 rows x 32 lanes x 4 floats per iteration)
#pragma unroll
    for (int it = 0; it < 8; ++it) {
      int lr16 = it * 2 + (lane >> 5);            // row within this 16-row pass
      int li = rbase + w * 32 + rt * 16 + lr16;   // list index
      bool valid = li < cnt;
      int gr = list[valid ? li : (cnt - 1)];
      float4 v = *(const float4*)(tb + (size_t)lr16 * CD + (lane & 31) * 4);
      if (valid) {
        size_t base = (size_t)gr * CD + (lane & 31) * 4;
        if (mode == 0) {
          uint2 pk;
          pk.x = (unsigned)f2bf(v.x) | ((unsigned)f2bf(v.y) << 16);
          pk.y = (unsigned)f2bf(v.z) | ((unsigned)f2bf(v.w) << 16);
          *(uint2*)(hout + base) = pk;
        } else {
          uint2 old = *(const uint2*)(xbf + base);
          float n0 = bf2f(old.x & 0xffffu) + v.x;
          float n1 = bf2f(old.x >> 16)     + v.y;
          float n2 = bf2f(old.y & 0xffffu) + v.z;
          float n3 = bf2f(old.y >> 16)     + v.w;
          uint2 pk;
          pk.x = (unsigned)f2bf(n0) | ((unsigned)f2bf(n1) << 16);
          pk.y = (unsigned)f2bf(n2) | ((unsigned)f2bf(n3) << 16);
          *(uint2*)(xbf + base) = pk;
          if (gr < nseed) {
            float4 xo = *(const float4*)(x32 + base);
            xo.x += v.x; xo.y += v.y; xo.z += v.z; xo.w += v.w;
            *(float4*)(x32 + base) = xo;
          }
        }
      }
    }
  }
}

// ---- head (reads fp32 seed mirror) ----
__global__ __launch_bounds__(256) void headk(const float* __restrict__ x,
    const float* __restrict__ hw, const float* __restrict__ hb,
    float* __restrict__ out, int seeds) {
  int wave = threadIdx.x >> 6;
  int lane = threadIdx.x & 63;
  int row = blockIdx.x * 4 + wave;
  if (row >= seeds) return;
  const float* xp = x + (size_t)row * CD;
  float v = xp[lane] * hw[lane] + xp[64 + lane] * hw[64 + lane];
#pragma unroll
  for (int m = 1; m < 64; m <<= 1) v += __shfl_xor(v, m, 64);
  if (lane == 0) out[row] = v + hb[0];
}

extern "C" void kernel_launch(void* const* d_in, const int* in_sizes, int n_in,
                              void* d_out, int out_size, void* d_ws, size_t ws_size,
                              hipStream_t stream) {
  const float* x     = (const float*)d_in[0];
  const int*   ntime = (const int*)d_in[1];
  const int*   eidx  = (const int*)d_in[2];
  const float* wroot = (const float*)d_in[3];
  const float* wnbr  = (const float*)d_in[4];
  const float* bias  = (const float*)d_in[5];
  const float* lng   = (const float*)d_in[6];
  const float* lnb   = (const float*)d_in[7];
  const float* headw = (const float*)d_in[8];
  const float* headb = (const float*)d_in[9];
  const int*   minp  = (const int*)d_in[10];
  const int*   up    = (const int*)d_in[12];

  int N = in_sizes[0] / CD;
  int E = in_sizes[2] / 2;
  const int P = 4;
  int M = P * N;
  int nseed = out_size;   // OUT=1 per reference

  size_t off = 0;
  auto alloc = [&](size_t bytes) {
    void* p = (char*)d_ws + off;
    off += (bytes + 255) & ~(size_t)255;
    return p;
  };
  unsigned short* x_bf   = (unsigned short*)alloc((size_t)N * CD * 2);
  unsigned short* h_bf   = (unsigned short*)alloc((size_t)N * CD * 2);
  unsigned short* agg_b  = (unsigned short*)alloc((size_t)N * CD * 2);
  float*          x32    = (float*)alloc((size_t)nseed * CD * 4);
  unsigned short* wt     = (unsigned short*)alloc(2 * 32768 * 2);
  int* deg_pd   = (int*)alloc((size_t)M * 4);
  int* row_ptr  = (int*)alloc((size_t)M * 4);
  int* col      = (int*)alloc((size_t)E * 4);
  int* involved = (int*)alloc((size_t)N * 4);
  int* lists    = (int*)alloc((size_t)M * 4);
  int* lcnt     = (int*)alloc(256);
  int* bsums    = (int*)alloc(4096);
  (void)ws_size;

  hipMemsetAsync(deg_pd, 0, (size_t)M * 4, stream);
  hipMemsetAsync(involved, 0, (size_t)N * 4, stream);
  hipMemsetAsync(lcnt, 0, 16, stream);

  int egrid = (E + 255) / 256;
  int ngrid = (N + 255) / 256;
  int NB = (M + 1023) / 1024;
  int ggrid = (N + 127) / 128;
  int agrid = (N + 15) / 16;

  xprep<<<(N * 32 + 255) / 256, 256, 0, stream>>>(x, x32, x_bf, nseed, N * 32);
  wprep<<<(8192 + 255) / 256, 256, 0, stream>>>(wroot, wnbr, wt, 8192);
  histk<<<egrid, 256, 0, stream>>>(ntime, eidx, deg_pd, involved, minp, up, N, E);
  listk<<<ngrid, 256, 0, stream>>>(involved, lists, lcnt, N);
  scan1<<<NB, 256, 0, stream>>>(deg_pd, row_ptr, bsums, M);
  scan2<<<1, 256, 0, stream>>>(bsums, NB);
  scan3<<<NB, 256, 0, stream>>>(row_ptr, bsums, M);
  fillk<<<egrid, 256, 0, stream>>>(ntime, eidx, row_ptr, col, minp, up, N, E);

  for (int p = 0; p < P; ++p) {
    const int* degp = deg_pd + (size_t)p * N;
    const int* lst  = lists + (size_t)p * N;
    const int* cp   = lcnt + p;
    aggk<<<agrid, 256, 0, stream>>>(x_bf, agg_b, row_ptr, deg_pd, col, p, N);
    gemm_mfma<<<ggrid, 256, 0, stream>>>(x_bf, agg_b, degp, wt,
        bias, lng, lnb, h_bf, nullptr, nullptr, lst, cp, 0, nseed, N);
    aggk<<<agrid, 256, 0, stream>>>(h_bf, agg_b, row_ptr, deg_pd, col, p, N);
    gemm_mfma<<<ggrid, 256, 0, stream>>>(h_bf, agg_b, degp, wt + 32768,
        bias + CD, lng + CD, lnb + CD, nullptr, x32, x_bf, lst, cp, 1, nseed, N);
  }
  headk<<<(nseed + 3) / 4, 256, 0, stream>>>(x32, headw, headb, (float*)d_out, nseed);
}